// Round 2
// baseline (100.561 us; speedup 1.0000x reference)
//
#include <hip/hip_runtime.h>

#define M_Q 16384
#define N_P 4096
#define C_F 64
#define WAVES_PER_BLOCK 4
#define BLOCK (WAVES_PER_BLOCK * 64)

// Wave-per-query ball query (first K=4 in scan order, r^2 = 1.0) fused with
// seg_feats max-pool gather + pillar_feature add.
//
// Round-1 change: removed ALL shared state (LDS staging + __syncthreads +
// 8-wave blocks). seg_points (48 KB) and seg_feats (1 MB) are L2-resident;
// lanes read them directly from global. Each wave is now a fully independent
// deterministic unit — nothing in the kernel can differ between launches.
//
// Exactness notes (validated bit-exact in round 1):
//  - All arithmetic feeding `d2 < 1.0f` uses __fmul_rn/__fadd_rn/__fsub_rn to
//    forbid FMA contraction (matches numpy IEEE f32 mul-then-add exactly).
//  - Reference pads empty slots with the FIRST found index, and
//    flag = (sum of idx) > 0 — a query whose only neighbor is point 0
//    contributes nothing. Replicated verbatim.
__global__ __launch_bounds__(BLOCK) void qf_kernel(
    const float* __restrict__ pillar,   // M x 64
    const int*   __restrict__ coors,    // M x 4 (b, z, y, x)
    const float* __restrict__ segf,     // N x 64
    const float* __restrict__ segp,     // N x 3
    float* __restrict__ out,            // M x 64
    int m_q)
{
    const int tid  = threadIdx.x;
    const int wave = tid >> 6;
    const int lane = tid & 63;
    const int q = blockIdx.x * WAVES_PER_BLOCK + wave;
    if (q >= m_q) return;

    // Query center: (c + 0.5) * 0.16 + pc_range  (mul then add, NO fma)
    const int cx = coors[q * 4 + 3];
    const int cy = coors[q * 4 + 2];
    const float qx = __fadd_rn(__fmul_rn(__fadd_rn((float)cx, 0.5f), 0.16f), 0.0f);
    const float qy = __fadd_rn(__fmul_rn(__fadd_rn((float)cy, 0.5f), 0.16f), -25.6f);

    int i0 = 0, i1 = 0, i2 = 0, i3 = 0;
    int found = 0;

    for (int step = 0; step < N_P / 64; ++step) {
        const int base = step * 64;
        const int p = base + lane;
        const float px = segp[3 * p + 0];
        const float py = segp[3 * p + 1];
        const float dx = __fsub_rn(qx, px);
        const float dy = __fsub_rn(qy, py);
        const float d2 = __fadd_rn(__fmul_rn(dx, dx), __fmul_rn(dy, dy));
        unsigned long long mask = __ballot(d2 < 1.0f);
        // mask is wave-uniform -> extraction below is uniform control flow.
        // Extract in-radius indices in ascending (scan) order.
        while (mask) {
            const int j = base + (int)__builtin_ctzll(mask);
            mask &= (mask - 1);
            if      (found == 0) i0 = j;
            else if (found == 1) i1 = j;
            else if (found == 2) i2 = j;
            else                 i3 = j;
            ++found;
            if (found == 4) break;
        }
        if (found == 4) break;
    }

    int flag = 0;
    if (found > 0) {
        if (found < 2) i1 = i0;
        if (found < 3) i2 = i0;
        if (found < 4) i3 = i0;
        flag = ((i0 + i1 + i2 + i3) > 0) ? 1 : 0;
    }

    // Epilogue: lane == channel (C == wave width == 64).
    float m = 0.0f;
    if (flag) {
        const float a = segf[i0 * C_F + lane];
        const float b = segf[i1 * C_F + lane];
        const float c = segf[i2 * C_F + lane];
        const float d = segf[i3 * C_F + lane];
        m = fmaxf(fmaxf(a, b), fmaxf(c, d));
    }
    out[q * C_F + lane] = pillar[q * C_F + lane] + m;
}

extern "C" void kernel_launch(void* const* d_in, const int* in_sizes, int n_in,
                              void* d_out, int out_size, void* d_ws, size_t ws_size,
                              hipStream_t stream) {
    const float* pillar = (const float*)d_in[0];
    const int*   coors  = (const int*)d_in[1];
    const float* segf   = (const float*)d_in[2];
    const float* segp   = (const float*)d_in[3];
    float* out = (float*)d_out;

    const int m_q = in_sizes[0] / C_F;  // 16384
    const int grid = (m_q + WAVES_PER_BLOCK - 1) / WAVES_PER_BLOCK;  // 4096
    qf_kernel<<<grid, BLOCK, 0, stream>>>(pillar, coors, segf, segp, out, m_q);
}

// Round 4
// 92.114 us; speedup vs baseline: 1.0917x; 1.0917x over previous
//
#include <hip/hip_runtime.h>

#define NPTS  4096
#define MQ    16384
#define CF    64
#define GRIDC 50
#define NCELLS (GRIDC * GRIDC)
#define CAP   32
#define INVCELL 0.9765625f   // 1/1.024, exact in binary — cell size 1.024 > radius 1.0

// ws layout (bytes)
#define OFF_COUNTS 0
#define OFF_BXY    10240                           // counts: 2500*4 -> rounded
#define OFF_BID    (OFF_BXY + NCELLS * CAP * 8)    // bucket xy: 640000
#define OFF_QIDX   (OFF_BID + NCELLS * CAP * 4)    // bucket id: 320000
// total = OFF_QIDX + MQ*16 = 1,232,384 B

// Ball query "first 4 in scan order" == "4 smallest indices of the in-radius
// set" (pad = first found = min index). Min-4 is enumeration-order-independent,
// so a spatial hash with atomic (nondeterministic-order) buckets still yields
// a bit-deterministic result.

__global__ void k_scatter(const float* __restrict__ segp,
                          int* __restrict__ counts,
                          float2* __restrict__ bxy,
                          int* __restrict__ bid) {
    int p = blockIdx.x * blockDim.x + threadIdx.x;
    if (p >= NPTS) return;
    float px = segp[3 * p + 0];
    float py = segp[3 * p + 1];
    int ix = (int)(px * INVCELL);
    int iy = (int)((py + 25.6f) * INVCELL);
    ix = min(max(ix, 0), GRIDC - 1);
    iy = min(max(iy, 0), GRIDC - 1);
    int cell = iy * GRIDC + ix;
    int slot = atomicAdd(&counts[cell], 1);
    if (slot < CAP) {
        bxy[cell * CAP + slot] = make_float2(px, py);
        bid[cell * CAP + slot] = p;
    }
}

__global__ void k_query(const int* __restrict__ coors,
                        const int* __restrict__ counts,
                        const float2* __restrict__ bxy,
                        const int* __restrict__ bid,
                        int4* __restrict__ qidx) {
    int q = blockIdx.x * blockDim.x + threadIdx.x;
    if (q >= MQ) return;
    int cx = coors[4 * q + 3];
    int cy = coors[4 * q + 2];
    // (c + 0.5) * 0.16 + pc_range — mul then add, NO fma (bit-exact vs numpy)
    float qx = __fadd_rn(__fmul_rn(__fadd_rn((float)cx, 0.5f), 0.16f), 0.0f);
    float qy = __fadd_rn(__fmul_rn(__fadd_rn((float)cy, 0.5f), 0.16f), -25.6f);
    int icx = (int)(qx * INVCELL);
    int icy = (int)((qy + 25.6f) * INVCELL);

    const int SENT = 0x7fffffff;
    int s0 = SENT, s1 = SENT, s2 = SENT, s3 = SENT;  // sorted 4 smallest

    for (int dy = -1; dy <= 1; ++dy) {
        int iy = icy + dy;
        if (iy < 0 || iy >= GRIDC) continue;
        for (int dx = -1; dx <= 1; ++dx) {
            int ix = icx + dx;
            if (ix < 0 || ix >= GRIDC) continue;
            int cell = iy * GRIDC + ix;
            int n = counts[cell];
            n = n > CAP ? CAP : n;
            int base = cell * CAP;
            for (int j = 0; j < n; ++j) {
                float2 pt = bxy[base + j];
                float ddx = __fsub_rn(qx, pt.x);
                float ddy = __fsub_rn(qy, pt.y);
                float d2 = __fadd_rn(__fmul_rn(ddx, ddx), __fmul_rn(ddy, ddy));
                if (d2 < 1.0f) {
                    int p = bid[base + j];
                    if (p < s3) {
                        if (p < s2) {
                            s3 = s2;
                            if (p < s1) {
                                s2 = s1;
                                if (p < s0) { s1 = s0; s0 = p; } else { s1 = p; }
                            } else { s2 = p; }
                        } else { s3 = p; }
                    }
                }
            }
        }
    }

    int4 r;
    if (s0 == SENT) {
        r.x = r.y = r.z = r.w = 0;           // no neighbor -> all zeros (ref)
    } else {
        r.x = s0;
        r.y = (s1 == SENT) ? s0 : s1;        // pad with FIRST (= min) index
        r.z = (s2 == SENT) ? s0 : s2;
        r.w = (s3 == SENT) ? s0 : s3;
    }
    qidx[q] = r;
}

__global__ __launch_bounds__(256) void k_epilogue(
    const float* __restrict__ pillar,
    const float* __restrict__ segf,
    const int4* __restrict__ qidx,
    float* __restrict__ out) {
    int tid  = threadIdx.x;
    int wave = tid >> 6;
    int lane = tid & 63;
    int q = blockIdx.x * 4 + wave;
    int4 v = qidx[q];                         // same addr across wave: broadcast
    float m = 0.0f;
    if ((v.x + v.y + v.z + v.w) > 0) {        // ref: flag = sum(idx) > 0
        float a = segf[v.x * CF + lane];
        float b = segf[v.y * CF + lane];
        float c = segf[v.z * CF + lane];
        float d = segf[v.w * CF + lane];
        m = fmaxf(fmaxf(a, b), fmaxf(c, d));
    }
    out[q * CF + lane] = pillar[q * CF + lane] + m;
}

extern "C" void kernel_launch(void* const* d_in, const int* in_sizes, int n_in,
                              void* d_out, int out_size, void* d_ws, size_t ws_size,
                              hipStream_t stream) {
    const float* pillar = (const float*)d_in[0];
    const int*   coors  = (const int*)d_in[1];
    const float* segf   = (const float*)d_in[2];
    const float* segp   = (const float*)d_in[3];
    float* out = (float*)d_out;

    char* ws = (char*)d_ws;
    int*    counts = (int*)(ws + OFF_COUNTS);
    float2* bxy    = (float2*)(ws + OFF_BXY);
    int*    bid    = (int*)(ws + OFF_BID);
    int4*   qidx   = (int4*)(ws + OFF_QIDX);

    hipMemsetAsync(counts, 0, NCELLS * sizeof(int), stream);
    k_scatter<<<(NPTS + 255) / 256, 256, 0, stream>>>(segp, counts, bxy, bid);
    k_query<<<(MQ + 255) / 256, 256, 0, stream>>>(coors, counts, bxy, bid, qidx);
    k_epilogue<<<MQ / 4, 256, 0, stream>>>(pillar, segf, qidx, out);
}

// Round 5
// 86.763 us; speedup vs baseline: 1.1590x; 1.0617x over previous
//
#include <hip/hip_runtime.h>

#define NPTS  4096
#define MQ    16384
#define CF    64
#define GRIDC 50
#define NCELLS (GRIDC * GRIDC)
#define CAP   32
#define INVCELL 0.9765625f   // 1/1.024, exact in binary; cell 1.024 > radius 1.0
#define SENT  0x7fffffff

// ws layout (bytes)
#define OFF_COUNTS 0
#define OFF_BKT    10240                  // counts: 2500*4 rounded up
// bkt: 2500 * 32 * 16 B = 1.28 MB; total ws use ~1.29 MB

// "First 4 in scan order" == "4 smallest indices of the in-radius set"
// (pad = first found = min index). Min-4 is enumeration-order-independent,
// so atomic (nondeterministic-order) bucket fill still yields bit-identical
// output every launch.

// Single-block build: zero counts, fence+barrier (only this block writes them
// this launch), then scatter. Packs (x, y, id) per slot so the query side does
// ONE 16B load per candidate.
__global__ __launch_bounds__(1024) void k_build(const float* __restrict__ segp,
                                                int* __restrict__ counts,
                                                float4* __restrict__ bkt) {
    const int tid = threadIdx.x;
    for (int c = tid; c < NCELLS; c += 1024) counts[c] = 0;
    __threadfence();
    __syncthreads();
    for (int p = tid; p < NPTS; p += 1024) {
        const float px = segp[3 * p + 0];
        const float py = segp[3 * p + 1];
        int ix = (int)(px * INVCELL);
        int iy = (int)((py + 25.6f) * INVCELL);
        ix = min(max(ix, 0), GRIDC - 1);
        iy = min(max(iy, 0), GRIDC - 1);
        const int cell = iy * GRIDC + ix;
        const int slot = atomicAdd(&counts[cell], 1);
        if (slot < CAP) {   // P(cell count > 32) ~ 1e-29 at lambda=1.64
            bkt[cell * CAP + slot] = make_float4(px, py, __int_as_float(p), 0.0f);
        }
    }
}

// Wave-per-query: lane-parallel candidate test + wave-min-4 + fused epilogue.
__global__ __launch_bounds__(256) void k_fused(
    const float* __restrict__ pillar,   // M x 64
    const int*   __restrict__ coors,    // M x 4 (b, z, y, x)
    const float* __restrict__ segf,     // N x 64
    const int*   __restrict__ counts,
    const float4* __restrict__ bkt,
    float* __restrict__ out)            // M x 64
{
    const int tid  = threadIdx.x;
    const int wave = tid >> 6;
    const int lane = tid & 63;
    const int q = blockIdx.x * 4 + wave;

    const int cx = coors[4 * q + 3];
    const int cy = coors[4 * q + 2];
    // (c + 0.5) * 0.16 + pc_range — mul then add, NO fma (bit-exact vs numpy)
    const float qx = __fadd_rn(__fmul_rn(__fadd_rn((float)cx, 0.5f), 0.16f), 0.0f);
    const float qy = __fadd_rn(__fmul_rn(__fadd_rn((float)cy, 0.5f), 0.16f), -25.6f);
    const int icx = (int)(qx * INVCELL);
    const int icy = (int)((qy + 25.6f) * INVCELL);
    // 3x3 window covers the r=1.0 ball: geometric margin >= 0.024 per edge,
    // f32 rounding is ~1e-6 — cells only select a candidate SUPERSET anyway.

    int cnt = 0, cbase = 0;
    if (lane < 9) {
        const int iy = icy + lane / 3 - 1;
        const int ix = icx + lane % 3 - 1;
        if (ix >= 0 && ix < GRIDC && iy >= 0 && iy < GRIDC) {
            const int cell = iy * GRIDC + ix;
            int n = counts[cell];
            cnt = n > CAP ? CAP : n;
            cbase = cell * CAP;
        }
    }

    int pre[10], bases[9];
    pre[0] = 0;
#pragma unroll
    for (int j = 0; j < 9; ++j) {
        pre[j + 1] = pre[j] + __shfl(cnt, j);
        bases[j] = __shfl(cbase, j);
    }
    const int total = pre[9];

    int r0 = SENT, r1 = SENT, r2 = SENT, r3 = SENT;  // sorted 4 smallest ids
    for (int b = 0; b < total; b += 64) {            // almost always 1 batch
        const int k = b + lane;
        int cand = SENT;
        if (k < total) {
            int addr = 0;
#pragma unroll
            for (int j = 0; j < 9; ++j) {
                if (k >= pre[j] && k < pre[j + 1]) addr = bases[j] + (k - pre[j]);
            }
            const float4 e = bkt[addr];
            const float dx = __fsub_rn(qx, e.x);
            const float dy = __fsub_rn(qy, e.y);
            const float d2 = __fadd_rn(__fmul_rn(dx, dx), __fmul_rn(dy, dy));
            if (d2 < 1.0f) cand = __float_as_int(e.z);
        }
#pragma unroll
        for (int r = 0; r < 4; ++r) {
            int v = cand;
            for (int off = 32; off; off >>= 1) v = min(v, __shfl_xor(v, off));
            if (v == SENT) break;                    // wave-uniform
            if (v < r3) {                            // sorted insert (ids unique)
                if (v < r2) {
                    r3 = r2;
                    if (v < r1) {
                        r2 = r1;
                        if (v < r0) { r1 = r0; r0 = v; } else { r1 = v; }
                    } else { r2 = v; }
                } else { r3 = v; }
            }
            if (cand == v) cand = SENT;
        }
    }

    int i0, i1, i2, i3, flag;
    if (r0 == SENT) {
        i0 = i1 = i2 = i3 = 0; flag = 0;             // no neighbor: ref = zeros
    } else {
        i0 = r0;
        i1 = (r1 == SENT) ? r0 : r1;                 // pad with FIRST (= min)
        i2 = (r2 == SENT) ? r0 : r2;
        i3 = (r3 == SENT) ? r0 : r3;
        flag = (i0 + i1 + i2 + i3) > 0;              // ref: sum(idx) > 0
    }

    float m = 0.0f;
    if (flag) {
        const float a = segf[i0 * CF + lane];
        const float b = segf[i1 * CF + lane];
        const float c = segf[i2 * CF + lane];
        const float d = segf[i3 * CF + lane];
        m = fmaxf(fmaxf(a, b), fmaxf(c, d));
    }
    out[q * CF + lane] = pillar[q * CF + lane] + m;
}

extern "C" void kernel_launch(void* const* d_in, const int* in_sizes, int n_in,
                              void* d_out, int out_size, void* d_ws, size_t ws_size,
                              hipStream_t stream) {
    const float* pillar = (const float*)d_in[0];
    const int*   coors  = (const int*)d_in[1];
    const float* segf   = (const float*)d_in[2];
    const float* segp   = (const float*)d_in[3];
    float* out = (float*)d_out;

    char* ws = (char*)d_ws;
    int*    counts = (int*)(ws + OFF_COUNTS);
    float4* bkt    = (float4*)(ws + OFF_BKT);

    k_build<<<1, 1024, 0, stream>>>(segp, counts, bkt);
    k_fused<<<MQ / 4, 256, 0, stream>>>(pillar, coors, segf, counts, bkt, out);
}